// Round 1
// baseline (477.971 us; speedup 1.0000x reference)
//
#include <hip/hip_runtime.h>

#define CH 128
#define MM 64
#define BB 128
#define NN 4096
#define KSPLIT 8
#define KCHUNK (NN / KSPLIT)   // 512
#define KU 8

// ---------------------------------------------------------------------------
// Kernel 1: h_hat[b][m][c] += sum_{k in chunk} U[b][k][m] * h[b*N+k][c]
// grid: BB*KSPLIT blocks, 256 threads. Thread computes 4m x 8c outputs.
// ---------------------------------------------------------------------------
__global__ __launch_bounds__(256) void k1_uth(const float* __restrict__ U,
                                              const float* __restrict__ h,
                                              float* __restrict__ h_hat) {
    __shared__ float Us[KU][MM];   // 8x64  = 2 KB
    __shared__ float Hs[KU][CH];   // 8x128 = 4 KB

    const int tid = threadIdx.x;
    const int bid = blockIdx.x;
    const int b   = bid >> 3;       // KSPLIT = 8
    const int ks  = bid & 7;
    const int k0  = ks * KCHUNK;

    const int mt = tid >> 4;        // 0..15  -> m = mt*4 .. +4
    const int ct = tid & 15;        // 0..15  -> c = ct*8 .. +8

    const float* Ub = U + (size_t)b * NN * MM;
    const float* hb = h + (size_t)b * NN * CH;

    float acc[4][8];
    #pragma unroll
    for (int i = 0; i < 4; ++i)
        #pragma unroll
        for (int j = 0; j < 8; ++j) acc[i][j] = 0.f;

    for (int kk = 0; kk < KCHUNK; kk += KU) {
        // U panel: 8 rows x 64 = 512 contiguous floats (m is fastest dim)
        const float* usrc = Ub + (size_t)(k0 + kk) * MM;
        ((float2*)&Us[0][0])[tid] = ((const float2*)usrc)[tid];
        // h panel: 8 rows x 128 = 1024 contiguous floats
        const float* hsrc = hb + (size_t)(k0 + kk) * CH;
        ((float4*)&Hs[0][0])[tid] = ((const float4*)hsrc)[tid];
        __syncthreads();

        #pragma unroll
        for (int ku = 0; ku < KU; ++ku) {
            float4 uv = *(const float4*)&Us[ku][mt * 4];
            float4 h0 = *(const float4*)&Hs[ku][ct * 8];
            float4 h1 = *(const float4*)&Hs[ku][ct * 8 + 4];
            float u[4]  = {uv.x, uv.y, uv.z, uv.w};
            float hv[8] = {h0.x, h0.y, h0.z, h0.w, h1.x, h1.y, h1.z, h1.w};
            #pragma unroll
            for (int i = 0; i < 4; ++i)
                #pragma unroll
                for (int j = 0; j < 8; ++j)
                    acc[i][j] += u[i] * hv[j];
        }
        __syncthreads();
    }

    float* dst = h_hat + (size_t)b * MM * CH;
    #pragma unroll
    for (int i = 0; i < 4; ++i) {
        const int m = mt * 4 + i;
        #pragma unroll
        for (int j = 0; j < 8; ++j) {
            const int c = ct * 8 + j;
            atomicAdd(&dst[m * CH + c], acc[i][j]);
        }
    }
}

// ---------------------------------------------------------------------------
// Kernel 2: out_hat[b][m][o] = sum_c h_hat[b][m][c] * W[m][c][o]
// grid: (MM, BB/16), 128 threads (one per o). 16 batches share each W row read.
// ---------------------------------------------------------------------------
__global__ __launch_bounds__(128) void k2_mix(const float* __restrict__ h_hat,
                                              const float* __restrict__ W,
                                              float* __restrict__ out_hat) {
    __shared__ float hs[16][CH];    // 8 KB
    const int tid = threadIdx.x;    // o
    const int m   = blockIdx.x;     // 0..63
    const int b0  = blockIdx.y * 16;

    #pragma unroll
    for (int i = 0; i < 16; ++i)
        hs[i][tid] = h_hat[((size_t)(b0 + i) * MM + m) * CH + tid];
    __syncthreads();

    float acc[16];
    #pragma unroll
    for (int i = 0; i < 16; ++i) acc[i] = 0.f;

    const float* Wm = W + (size_t)m * CH * CH;
    for (int c = 0; c < CH; ++c) {
        const float w = Wm[c * CH + tid];
        #pragma unroll
        for (int i = 0; i < 16; ++i) acc[i] += hs[i][c] * w;
    }

    #pragma unroll
    for (int i = 0; i < 16; ++i)
        out_hat[((size_t)(b0 + i) * MM + m) * CH + tid] = acc[i];
}

// ---------------------------------------------------------------------------
// Kernel 3: out[b][n][o] = sum_m U[b][n][m] * out_hat[b][m][o]
// grid: (NN/64, BB), 256 threads. Thread computes 4n x 8o outputs.
// ---------------------------------------------------------------------------
__global__ __launch_bounds__(256) void k3_back(const float* __restrict__ U,
                                               const float* __restrict__ out_hat,
                                               float* __restrict__ out) {
    __shared__ float oh[MM][CH];    // 64x128 = 32 KB
    __shared__ float Usz[64][65];   // padded: kills 32-way conflict on [n][m] read

    const int tid = threadIdx.x;
    const int n0  = blockIdx.x * 64;
    const int b   = blockIdx.y;

    // stage out_hat[b] (8192 floats) linearly
    {
        const float4* src = (const float4*)(out_hat + (size_t)b * MM * CH);
        float4* dst = (float4*)&oh[0][0];
        #pragma unroll
        for (int i = 0; i < 8; ++i)
            dst[tid + i * 256] = src[tid + i * 256];
    }
    // stage U tile: 64 rows x 64 m, padded stride 65
    {
        const int r0   = tid >> 4;   // 0..15
        const int lane = tid & 15;   // 0..15, 4 floats each
        #pragma unroll
        for (int p = 0; p < 4; ++p) {
            const int r = r0 + p * 16;
            const float* src = U + ((size_t)b * NN + n0 + r) * MM + lane * 4;
            float4 v = *(const float4*)src;
            Usz[r][lane * 4 + 0] = v.x;
            Usz[r][lane * 4 + 1] = v.y;
            Usz[r][lane * 4 + 2] = v.z;
            Usz[r][lane * 4 + 3] = v.w;
        }
    }
    __syncthreads();

    const int nt = tid >> 4;    // 0..15 -> n = nt + {0,16,32,48}
    const int ot = tid & 15;    // 0..15 -> o = ot*8 .. +8

    float acc[4][8];
    #pragma unroll
    for (int i = 0; i < 4; ++i)
        #pragma unroll
        for (int j = 0; j < 8; ++j) acc[i][j] = 0.f;

    for (int m = 0; m < MM; ++m) {
        float4 h0 = *(const float4*)&oh[m][ot * 8];
        float4 h1 = *(const float4*)&oh[m][ot * 8 + 4];
        float hv[8] = {h0.x, h0.y, h0.z, h0.w, h1.x, h1.y, h1.z, h1.w};
        float u[4];
        #pragma unroll
        for (int j = 0; j < 4; ++j) u[j] = Usz[nt + 16 * j][m];
        #pragma unroll
        for (int j = 0; j < 4; ++j)
            #pragma unroll
            for (int jj = 0; jj < 8; ++jj)
                acc[j][jj] += u[j] * hv[jj];
    }

    float* dst = out + ((size_t)b * NN + n0) * CH;
    #pragma unroll
    for (int j = 0; j < 4; ++j) {
        const int n = nt + 16 * j;
        *(float4*)&dst[n * CH + ot * 8]     = make_float4(acc[j][0], acc[j][1], acc[j][2], acc[j][3]);
        *(float4*)&dst[n * CH + ot * 8 + 4] = make_float4(acc[j][4], acc[j][5], acc[j][6], acc[j][7]);
    }
}

// ---------------------------------------------------------------------------
extern "C" void kernel_launch(void* const* d_in, const int* in_sizes, int n_in,
                              void* d_out, int out_size, void* d_ws, size_t ws_size,
                              hipStream_t stream) {
    const float* h = (const float*)d_in[0];   // [B*N, C]
    const float* U = (const float*)d_in[1];   // [B, N, M]
    const float* W = (const float*)d_in[2];   // [M, C, C]
    // d_in[3] = ptr (int64) — equal segments, constants baked in.
    float* out = (float*)d_out;

    float* h_hat   = (float*)d_ws;                            // B*M*C fp32 = 4 MB
    float* out_hat = h_hat + (size_t)BB * MM * CH;            // B*M*C fp32 = 4 MB

    hipMemsetAsync(h_hat, 0, (size_t)BB * MM * CH * sizeof(float), stream);

    k1_uth<<<BB * KSPLIT, 256, 0, stream>>>(U, h, h_hat);
    k2_mix<<<dim3(MM, BB / 16), 128, 0, stream>>>(h_hat, W, out_hat);
    k3_back<<<dim3(NN / 64, BB), 256, 0, stream>>>(U, out_hat, out);
}

// Round 3
// 283.757 us; speedup vs baseline: 1.6844x; 1.6844x over previous
//
#include <hip/hip_runtime.h>

#define CH 128
#define MM 64
#define BB 128
#define NN 4096
#define KSPLIT 16
#define KCHUNK (NN / KSPLIT)   // 256
#define KU 16
#define NIT (KCHUNK / KU)      // 16

#define AS1(p) ((const __attribute__((address_space(1))) void*)(p))
#define AS3(p) ((__attribute__((address_space(3))) void*)(p))

__device__ __forceinline__ void gl_lds16(const float* g, float* l) {
    __builtin_amdgcn_global_load_lds(AS1(g), AS3(l), 16, 0, 0);
}

// ---------------------------------------------------------------------------
// Kernel 1: partial[b][ks][m][c] = sum_{k in chunk ks} U[b][k][m] * h[b*N+k][c]
// grid: BB*KSPLIT = 2048 blocks, 256 threads. Thread: 4m x 8c outputs.
// Double-buffered LDS via global_load_lds + counted vmcnt (T3/T4 minimum form).
// ---------------------------------------------------------------------------
__global__ __launch_bounds__(256) void k1_uth(const float* __restrict__ U,
                                              const float* __restrict__ h,
                                              float* __restrict__ hhp) {
    // panel layout: [0..1023] = U 16x64, [1024..3071] = h 16x128
    __shared__ float panel[2][3072];   // 24 KB total

    const int tid = threadIdx.x;
    const int bid = blockIdx.x;
    const int b   = bid >> 4;        // KSPLIT = 16
    const int ks  = bid & 15;
    const int k0  = ks * KCHUNK;

    const int mt = tid >> 4;         // m = mt*4 .. +3
    const int ct = tid & 15;         // c in {ct*4..+3} and {64+ct*4..+3}

    const float* Ub = U + ((size_t)b * NN + k0) * MM;
    const float* hb = h + ((size_t)b * NN + k0) * CH;

    float acc[4][8];
    #pragma unroll
    for (int i = 0; i < 4; ++i)
        #pragma unroll
        for (int j = 0; j < 8; ++j) acc[i][j] = 0.f;

    auto stage = [&](int p, int it) {
        const float* us = Ub + (size_t)it * KU * MM;   // 1024 floats, contiguous
        const float* hs = hb + (size_t)it * KU * CH;   // 2048 floats, contiguous
        gl_lds16(us + tid * 4,        &panel[p][tid * 4]);
        gl_lds16(hs + tid * 4,        &panel[p][1024 + tid * 4]);
        gl_lds16(hs + 1024 + tid * 4, &panel[p][2048 + tid * 4]);
    };

    auto compute = [&](const float* __restrict__ P) {
        #pragma unroll
        for (int ku = 0; ku < KU; ++ku) {
            float4 uv = *(const float4*)&P[ku * 64 + mt * 4];
            float4 h0 = *(const float4*)&P[1024 + ku * 128 + ct * 4];
            float4 h1 = *(const float4*)&P[1024 + ku * 128 + 64 + ct * 4];
            float u[4]  = {uv.x, uv.y, uv.z, uv.w};
            float hv[8] = {h0.x, h0.y, h0.z, h0.w, h1.x, h1.y, h1.z, h1.w};
            #pragma unroll
            for (int i = 0; i < 4; ++i)
                #pragma unroll
                for (int j = 0; j < 8; ++j)
                    acc[i][j] += u[i] * hv[j];
        }
    };

    stage(0, 0);
    #pragma unroll 1
    for (int it = 0; it < NIT - 1; ++it) {
        stage((it + 1) & 1, it + 1);
        asm volatile("s_waitcnt vmcnt(3)" ::: "memory");   // cur panel landed
        __builtin_amdgcn_s_barrier();
        __builtin_amdgcn_sched_barrier(0);
        compute(panel[it & 1]);
        __builtin_amdgcn_s_barrier();                      // all done reading cur
    }
    asm volatile("s_waitcnt vmcnt(0)" ::: "memory");
    __builtin_amdgcn_s_barrier();
    __builtin_amdgcn_sched_barrier(0);
    compute(panel[(NIT - 1) & 1]);

    // non-atomic partial write: block owns partial (b,ks) entirely
    float* dst = hhp + (size_t)(b * KSPLIT + ks) * MM * CH;
    #pragma unroll
    for (int i = 0; i < 4; ++i) {
        const int m = mt * 4 + i;
        *(float4*)&dst[m * CH + ct * 4] =
            make_float4(acc[i][0], acc[i][1], acc[i][2], acc[i][3]);
        *(float4*)&dst[m * CH + 64 + ct * 4] =
            make_float4(acc[i][4], acc[i][5], acc[i][6], acc[i][7]);
    }
}

// ---------------------------------------------------------------------------
// Kernel 2: out_hat[b][m][o] = sum_c (sum_ks partial[b][ks][m][c]) * W[m][c][o]
// grid: (MM, BB/16) = (64, 8), 256 threads (2 halves x 128 o-lanes, 8 b each).
// ---------------------------------------------------------------------------
__global__ __launch_bounds__(256) void k2_mix(const float* __restrict__ hhp,
                                              const float* __restrict__ W,
                                              float* __restrict__ out_hat) {
    __shared__ float hs[16][CH];     // 8 KB
    const int tid  = threadIdx.x;
    const int o    = tid & 127;
    const int half = tid >> 7;       // 0/1 -> batches [0..8) / [8..16)
    const int m    = blockIdx.x;
    const int b0   = blockIdx.y * 16;

    #pragma unroll
    for (int i = 0; i < 8; ++i) {
        const int b = b0 + half * 8 + i;
        const float* src = hhp + ((size_t)(b * KSPLIT) * MM + m) * CH + o;
        float s = 0.f;
        #pragma unroll
        for (int ksi = 0; ksi < KSPLIT; ++ksi)
            s += src[(size_t)ksi * MM * CH];
        hs[half * 8 + i][o] = s;
    }
    __syncthreads();

    float acc[8];
    #pragma unroll
    for (int i = 0; i < 8; ++i) acc[i] = 0.f;

    const float* Wm = W + (size_t)m * CH * CH;
    for (int c = 0; c < CH; ++c) {
        const float w = Wm[c * CH + o];
        #pragma unroll
        for (int i = 0; i < 8; ++i) acc[i] += hs[half * 8 + i][c] * w;
    }

    #pragma unroll
    for (int i = 0; i < 8; ++i)
        out_hat[((size_t)(b0 + half * 8 + i) * MM + m) * CH + o] = acc[i];
}

// ---------------------------------------------------------------------------
// Kernel 3: out[b][n][o] = sum_m U[b][n][m] * out_hat[b][m][o]
// grid: (NN/64, BB) = (64, 128), 256 threads. Thread: 4 consecutive n x 8 o.
// U staged transposed (stride 68 -> 16B-aligned float4 rows, bank-rotated).
// ---------------------------------------------------------------------------
__global__ __launch_bounds__(256) void k3_back(const float* __restrict__ U,
                                               const float* __restrict__ out_hat,
                                               float* __restrict__ out) {
    __shared__ float oh[MM][CH];     // 32 KB
    __shared__ float Ut[MM][68];     // transposed U tile, padded: 17 KB

    const int tid = threadIdx.x;
    const int n0  = blockIdx.x * 64;
    const int b   = blockIdx.y;

    // stage out_hat[b]: 8192 floats, linear float4
    {
        const float4* src = (const float4*)(out_hat + (size_t)b * MM * CH);
        float4* dst = (float4*)&oh[0][0];
        #pragma unroll
        for (int i = 0; i < 8; ++i)
            dst[tid + i * 256] = src[tid + i * 256];
    }
    // stage U^T: each thread reads 16 floats of one U row, scatters to columns
    {
        const int r    = tid >> 2;          // row n (0..63)
        const int lane = tid & 3;           // 16 m's each
        const float* s = U + ((size_t)b * NN + n0 + r) * MM + lane * 16;
        float4 v0 = *(const float4*)(s + 0);
        float4 v1 = *(const float4*)(s + 4);
        float4 v2 = *(const float4*)(s + 8);
        float4 v3 = *(const float4*)(s + 12);
        const int m0 = lane * 16;
        Ut[m0 +  0][r] = v0.x; Ut[m0 +  1][r] = v0.y;
        Ut[m0 +  2][r] = v0.z; Ut[m0 +  3][r] = v0.w;
        Ut[m0 +  4][r] = v1.x; Ut[m0 +  5][r] = v1.y;
        Ut[m0 +  6][r] = v1.z; Ut[m0 +  7][r] = v1.w;
        Ut[m0 +  8][r] = v2.x; Ut[m0 +  9][r] = v2.y;
        Ut[m0 + 10][r] = v2.z; Ut[m0 + 11][r] = v2.w;
        Ut[m0 + 12][r] = v3.x; Ut[m0 + 13][r] = v3.y;
        Ut[m0 + 14][r] = v3.z; Ut[m0 + 15][r] = v3.w;
    }
    __syncthreads();

    const int nt = tid >> 4;    // n = nt*4 .. +3 (consecutive)
    const int ot = tid & 15;    // o in {ot*4..+3} and {64+ot*4..+3}

    float acc[4][8];
    #pragma unroll
    for (int i = 0; i < 4; ++i)
        #pragma unroll
        for (int j = 0; j < 8; ++j) acc[i][j] = 0.f;

    #pragma unroll 4
    for (int m = 0; m < MM; ++m) {
        float4 uv = *(const float4*)&Ut[m][nt * 4];
        float4 h0 = *(const float4*)&oh[m][ot * 4];
        float4 h1 = *(const float4*)&oh[m][64 + ot * 4];
        float u[4]  = {uv.x, uv.y, uv.z, uv.w};
        float hv[8] = {h0.x, h0.y, h0.z, h0.w, h1.x, h1.y, h1.z, h1.w};
        #pragma unroll
        for (int i = 0; i < 4; ++i)
            #pragma unroll
            for (int j = 0; j < 8; ++j)
                acc[i][j] += u[i] * hv[j];
    }

    float* dst = out + ((size_t)b * NN + n0) * CH;
    #pragma unroll
    for (int i = 0; i < 4; ++i) {
        const int n = nt * 4 + i;
        *(float4*)&dst[n * CH + ot * 4] =
            make_float4(acc[i][0], acc[i][1], acc[i][2], acc[i][3]);
        *(float4*)&dst[n * CH + 64 + ot * 4] =
            make_float4(acc[i][4], acc[i][5], acc[i][6], acc[i][7]);
    }
}

// ---------------------------------------------------------------------------
extern "C" void kernel_launch(void* const* d_in, const int* in_sizes, int n_in,
                              void* d_out, int out_size, void* d_ws, size_t ws_size,
                              hipStream_t stream) {
    const float* h = (const float*)d_in[0];   // [B*N, C]
    const float* U = (const float*)d_in[1];   // [B, N, M]
    const float* W = (const float*)d_in[2];   // [M, C, C]
    float* out = (float*)d_out;

    // partials live in d_out (67 MB of its 268 MB); k3 overwrites all of d_out.
    float* hhp     = (float*)d_out;           // [B*KSPLIT, M, C]
    float* out_hat = (float*)d_ws;            // [B, M, C] = 4 MB

    k1_uth<<<BB * KSPLIT, 256, 0, stream>>>(U, h, hhp);
    k2_mix<<<dim3(MM, BB / 16), 256, 0, stream>>>(hhp, W, out_hat);
    k3_back<<<dim3(NN / 64, BB), 256, 0, stream>>>(U, out_hat, out);
}